// Round 7
// baseline (243.412 us; speedup 1.0000x reference)
//
#include <hip/hip_runtime.h>

// Problem constants (HyperNetwork_9990093931021)
#define BB 256   // batch
#define CC 512   // channels
#define NZ 256   // flattened spatial (16*16)
#define ZD 64    // z_dim
#define KK 9     // out_c * f * f = 1*3*3
#define WFSZ (KK * NZ)   // fused weight elems per channel = 2304

// ---- DPP cross-lane add helpers (VALU-only) ----
template<int CTRL>
__device__ __forceinline__ float dpp_add(float v) {
    int o = __builtin_amdgcn_update_dpp(0, __float_as_int(v), CTRL, 0xF, 0xF, true);
    return v + __int_as_float(o);
}
__device__ __forceinline__ float red16(float v) {   // sum over aligned 16-lane group
    v = dpp_add<0xB1>(v);    // quad_perm [1,0,3,2]
    v = dpp_add<0x4E>(v);    // quad_perm [2,3,0,1]
    v = dpp_add<0x141>(v);   // row_half_mirror
    v = dpp_add<0x140>(v);   // row_mirror
    return v;
}

__device__ __forceinline__ unsigned short f2bf(float f) {   // RNE fp32->bf16
    unsigned u = __float_as_uint(f);
    u += 0x7FFF + ((u >> 16) & 1);
    return (unsigned short)(u >> 16);
}
__device__ __forceinline__ float bf2f(unsigned short h) {
    return __uint_as_float((unsigned)h << 16);
}

// ---- Kernel A: fused weight (bf16) + fused bias (fp32) into workspace ----
__global__ __launch_bounds__(512, 2)
void wf_kernel(const float* __restrict__ W_in, const float* __restrict__ b_in,
               const float* __restrict__ W_out, const float* __restrict__ b_out,
               unsigned short* __restrict__ wfb, float* __restrict__ biask) {
    __shared__ __align__(16) float s_woutT[KK * ZD]; // [k][z]
    __shared__ float s_bin[ZD];
    const int c = blockIdx.x;
    const int t = threadIdx.x;

    for (int i = t; i < KK * ZD; i += 512) {
        float v = W_out[i];
        int zz = i / KK, k = i - zz * KK;
        s_woutT[k * ZD + zz] = v;
    }
    if (t < ZD) s_bin[t] = b_in[c * ZD + t];
    __syncthreads();

    const int n = t >> 1, half = t & 1;
    const float* wrow = W_in + ((size_t)c * NZ + n) * ZD + half * 32;
    float acc[KK];
#pragma unroll
    for (int k = 0; k < KK; ++k) acc[k] = 0.f;
#pragma unroll
    for (int j = 0; j < 8; ++j) {
        const float4 w = *reinterpret_cast<const float4*>(wrow + 4 * j);
#pragma unroll
        for (int k = 0; k < KK; ++k) {
            const float4 wo = *reinterpret_cast<const float4*>(
                &s_woutT[k * ZD + half * 32 + 4 * j]);
            acc[k] += w.x * wo.x + w.y * wo.y + w.z * wo.z + w.w * wo.w;
        }
    }
#pragma unroll
    for (int k = 0; k < KK; ++k) acc[k] = dpp_add<0xB1>(acc[k]); // half0+half1
    if (half == 0) {
#pragma unroll
        for (int k = 0; k < KK; ++k)
            wfb[((size_t)c * KK + k) * NZ + n] = f2bf(acc[k]);
    }
    if (t < KK) {
        float s = 0.f;
        for (int zz = 0; zz < ZD; ++zz) s += s_bin[zz] * s_woutT[t * ZD + zz];
        biask[c * KK + t] = s + b_out[t];
    }
}

// ---- Kernel B: b-major, fully-linear z stream; Wf from L2 (bf16) ----
// grid = 2048 (c-chunk fast: 16 chunks x 128 b-pairs), block = 256 (4 waves).
// Block owns 2 b x 32 c -> z = two contiguous 32 KB stripes. No LDS, no
// barriers; 8 blocks/CU = 32 waves/CU free-running (the fill's profile).
// 16-lane group per (b,c) row; 4 rows per wave-step; rows of a step pair the
// two b's of the SAME c -> each wf load broadcasts across 2 groups (L2 hit).
__global__ __launch_bounds__(256, 6)
void out_kernel(const float* __restrict__ z, const unsigned short* __restrict__ wfb,
                const float* __restrict__ biask, float* __restrict__ out) {
    const int bid = blockIdx.x;
    const int b0 = (bid >> 4) * 2;        // 128 b-pairs
    const int cbase = (bid & 15) * 32;    // 16 c-chunks of 32

    const int t = threadIdx.x;
    const int wave = t >> 6;
    const int lane = t & 63;
    const int g = lane >> 4;              // row-slot 0..3
    const int s16 = lane & 15;            // 16 B n-slice within the row

    const int b = b0 + (g & 1);           // groups 0/2 -> b0, 1/3 -> b0+1
    const int cofs = g >> 1;              // groups 0,1 -> c; 2,3 -> c+1

#pragma unroll 1
    for (int s = 0; s < 4; ++s) {
        const int c = cbase + wave * 8 + s * 2 + cofs;
        const float* zr = z + ((size_t)b * CC + c) * NZ + s16 * 4;

        // full row in registers: 4 x float4 (256 B per 16-lane group per j)
        float4 x[4];
#pragma unroll
        for (int j = 0; j < 4; ++j)
            x[j] = *reinterpret_cast<const float4*>(zr + j * 64);

        const unsigned short* wr = wfb + (size_t)c * WFSZ + s16 * 4;
        float a[KK];
#pragma unroll
        for (int k = 0; k < KK; ++k) {
            float acc = 0.f;
#pragma unroll
            for (int j = 0; j < 4; ++j) {
                const ushort4 w4 = *reinterpret_cast<const ushort4*>(
                    wr + k * NZ + j * 64);             // 128 B/group, L2-hot
                acc += x[j].x * bf2f(w4.x) + x[j].y * bf2f(w4.y)
                     + x[j].z * bf2f(w4.z) + x[j].w * bf2f(w4.w);
            }
            a[k] = acc;
        }

#pragma unroll
        for (int k = 0; k < KK; ++k) a[k] = red16(a[k]);

        float v = a[0];
#pragma unroll
        for (int k = 1; k < KK; ++k) {
            if (s16 == k) v = a[k];                    // cndmask chain
        }
        if (s16 < KK) {
            v += biask[c * KK + s16];                  // L2-hot scalar
            out[((size_t)b * CC + c) * KK + s16] = v;  // block-contiguous overall
        }
    }
}

extern "C" void kernel_launch(void* const* d_in, const int* in_sizes, int n_in,
                              void* d_out, int out_size, void* d_ws, size_t ws_size,
                              hipStream_t stream) {
    const float* z     = (const float*)d_in[0];
    const float* W_in  = (const float*)d_in[1];
    const float* b_in  = (const float*)d_in[2];
    const float* W_out = (const float*)d_in[3];
    const float* b_out = (const float*)d_in[4];
    float* out = (float*)d_out;

    unsigned short* wfb = (unsigned short*)d_ws;                 // 512*2304 bf16 = 2.36 MB
    float* biask = (float*)((char*)d_ws + (size_t)CC * WFSZ * 2); // 18 KB fp32

    wf_kernel<<<dim3(CC), dim3(512), 0, stream>>>(W_in, b_in, W_out, b_out, wfb, biask);
    out_kernel<<<dim3(2048), dim3(256), 0, stream>>>(z, wfb, biask, out);
}